// Round 3
// baseline (203.613 us; speedup 1.0000x reference)
//
#include <hip/hip_runtime.h>
#include <math.h>

// YOLO loss — max-concurrency, no-LDS discriminator.
// Theory (R3): R0/R1/R2 (three different structures, occ 36-66%) all sit at
// ~2.8 TB/s effective read. Either (a) burst-drain-exit duty cycle + the
// mask->tcls dependency chain caps in-flight bytes, or (b) a per-CU request
// throughput wall. This kernel removes every structural limiter at once:
// 1 cell/thread, zero LDS (per-lane aligned float2 loads; every 128B line
// still fully consumed), unconditional tcls (no mask dependency), no
// barrier before the final reduce, ~72 VGPR -> ~24 waves/CU. If this does
// not move, the ~2.85 TB/s wall is the roofline.

#define BLOCK 256
#define WPB 4

__global__ __launch_bounds__(BLOCK, 6) void k_yolo(
    const float*  __restrict__ pred,
    const float4* __restrict__ tbox4,
    const float4* __restrict__ tcls4,
    const int*    __restrict__ mask,
    float4*       __restrict__ partial,
    int n_cells)
{
    const int tid  = threadIdx.x;
    const int cell = blockIdx.x * BLOCK + tid;
    const bool valid = cell < n_cells;

    float cls = 0.f, noobj = 0.f, reg = 0.f, cont = 0.f;

    if (valid) {
        const float2* pc2 = reinterpret_cast<const float2*>(pred + (size_t)cell * 30);
        const float4* t4  = tcls4 + (size_t)cell * 5;

        // ---- 22 independent loads (~220 B/lane in flight), no dependencies ----
        const int    mflag = mask[cell];
        const float4 tb    = tbox4[cell];
        float2 v0  = pc2[0],  v1  = pc2[1],  v2  = pc2[2],  v3  = pc2[3],  v4  = pc2[4];
        float2 v5  = pc2[5],  v6  = pc2[6],  v7  = pc2[7],  v8  = pc2[8],  v9  = pc2[9];
        float2 v10 = pc2[10], v11 = pc2[11], v12 = pc2[12], v13 = pc2[13], v14 = pc2[14];
        float4 tc0 = t4[0], tc1 = t4[1], tc2 = t4[2], tc3 = t4[3], tc4 = t4[4];

        // floats 0..9: box0 = (v0.x,v0.y,v1.x,v1.y, conf v2.x)
        //              box1 = (v2.y,v3.x,v3.y,v4.x, conf v4.y)
        if (mflag) {
            float txc = tb.x / 14.0f, tyc = tb.y / 14.0f;
            float t0 = txc - 0.5f * tb.z, t1 = tyc - 0.5f * tb.w;
            float t2c = txc + 0.5f * tb.z, t3 = tyc + 0.5f * tb.w;
            float area_t = (t2c - t0) * (t3 - t1);
            float bx[2] = { v0.x, v2.y }, by[2] = { v0.y, v3.x };
            float bw[2] = { v1.x, v3.y }, bh[2] = { v1.y, v4.x };
            float bcf[2] = { v2.x, v4.y };
            float iou[2];
            #pragma unroll
            for (int b = 0; b < 2; ++b) {
                float px = bx[b] / 14.0f, py = by[b] / 14.0f;
                float q0 = px - 0.5f * bw[b], q1 = py - 0.5f * bh[b];
                float q2 = px + 0.5f * bw[b], q3 = py + 0.5f * bh[b];
                float lt0 = fmaxf(t0, q0), lt1 = fmaxf(t1, q1);
                float rb0 = fminf(t2c, q2), rb1 = fminf(t3, q3);
                float ww = fmaxf(rb0 - lt0, 0.f), hh = fmaxf(rb1 - lt1, 0.f);
                float inter = ww * hh;
                float area_p = (q2 - q0) * (q3 - q1);
                iou[b] = inter / (area_t + area_p - inter);
            }
            int bi = (iou[1] > iou[0]) ? 1 : 0;   // first-max tie rule
            float dx = bx[bi] - tb.x, dy = by[bi] - tb.y;
            float swd = sqrtf(bw[bi]) - sqrtf(tb.z);
            float shd = sqrtf(bh[bi]) - sqrtf(tb.w);
            reg = 5.0f * (dx*dx + dy*dy + swd*swd + shd*shd);
            float dco = iou[bi] - bcf[bi];
            cont = dco * dco;

            // class floats k0..k19 = v5..v14 ; tcls = tc0..tc4
            float d;
            d = tc0.x - v5.x;  cls = fmaf(d, d, cls);
            d = tc0.y - v5.y;  cls = fmaf(d, d, cls);
            d = tc0.z - v6.x;  cls = fmaf(d, d, cls);
            d = tc0.w - v6.y;  cls = fmaf(d, d, cls);
            d = tc1.x - v7.x;  cls = fmaf(d, d, cls);
            d = tc1.y - v7.y;  cls = fmaf(d, d, cls);
            d = tc1.z - v8.x;  cls = fmaf(d, d, cls);
            d = tc1.w - v8.y;  cls = fmaf(d, d, cls);
            d = tc2.x - v9.x;  cls = fmaf(d, d, cls);
            d = tc2.y - v9.y;  cls = fmaf(d, d, cls);
            d = tc2.z - v10.x; cls = fmaf(d, d, cls);
            d = tc2.w - v10.y; cls = fmaf(d, d, cls);
            d = tc3.x - v11.x; cls = fmaf(d, d, cls);
            d = tc3.y - v11.y; cls = fmaf(d, d, cls);
            d = tc3.z - v12.x; cls = fmaf(d, d, cls);
            d = tc3.w - v12.y; cls = fmaf(d, d, cls);
            d = tc4.x - v13.x; cls = fmaf(d, d, cls);
            d = tc4.y - v13.y; cls = fmaf(d, d, cls);
            d = tc4.z - v14.x; cls = fmaf(d, d, cls);
            d = tc4.w - v14.y; cls = fmaf(d, d, cls);
        } else {
            noobj = 0.5f * (v2.x * v2.x + v4.y * v4.y);
        }
    }

    // ---- wave shuffle reduce, then block reduce, store partial ----
    #pragma unroll
    for (int off = 32; off; off >>= 1) {
        cls   += __shfl_down(cls,   off, 64);
        noobj += __shfl_down(noobj, off, 64);
        reg   += __shfl_down(reg,   off, 64);
        cont  += __shfl_down(cont,  off, 64);
    }
    __shared__ float4 swr[WPB];
    const int lane = tid & 63, w = tid >> 6;
    if (lane == 0) swr[w] = make_float4(cls, noobj, reg, cont);
    __syncthreads();
    if (tid == 0) {
        float4 a = swr[0];
        #pragma unroll
        for (int i = 1; i < WPB; ++i) {
            float4 b = swr[i];
            a.x += b.x; a.y += b.y; a.z += b.z; a.w += b.w;
        }
        partial[blockIdx.x] = a;
    }
}

__global__ __launch_bounds__(BLOCK) void k_final(
    const float4* __restrict__ partial, int nblocks,
    float* __restrict__ out, float invN)
{
    float4 acc = make_float4(0.f, 0.f, 0.f, 0.f);
    for (int b = threadIdx.x; b < nblocks; b += BLOCK) {
        float4 v = partial[b];
        acc.x += v.x; acc.y += v.y; acc.z += v.z; acc.w += v.w;
    }
    #pragma unroll
    for (int off = 32; off; off >>= 1) {
        acc.x += __shfl_down(acc.x, off, 64);
        acc.y += __shfl_down(acc.y, off, 64);
        acc.z += __shfl_down(acc.z, off, 64);
        acc.w += __shfl_down(acc.w, off, 64);
    }
    __shared__ float4 sw[WPB];
    int lane = threadIdx.x & 63, w = threadIdx.x >> 6;
    if (lane == 0) sw[w] = acc;
    __syncthreads();
    if (threadIdx.x == 0) {
        float cls = 0.f, noobj = 0.f, reg = 0.f, cont = 0.f;
        #pragma unroll
        for (int i = 0; i < WPB; ++i) {
            cls += sw[i].x; noobj += sw[i].y; reg += sw[i].z; cont += sw[i].w;
        }
        out[0] = (cls + noobj + reg + cont) * invN;
        out[1] = reg;
        out[2] = cont;
        out[3] = noobj;
        out[4] = cls;
    }
}

extern "C" void kernel_launch(void* const* d_in, const int* in_sizes, int n_in,
                              void* d_out, int out_size, void* d_ws, size_t ws_size,
                              hipStream_t stream) {
    const float*  pred  = (const float*)d_in[0];   // (N,14,14,30) f32
    const float4* tbox4 = (const float4*)d_in[1];  // (N,14,14,4)  f32
    const float4* tcls4 = (const float4*)d_in[2];  // (N,14,14,20) f32
    const int*    mask  = (const int*)d_in[3];     // (N,14,14)    int32
    float* out = (float*)d_out;
    float4* partial = (float4*)d_ws;

    int n_cells = in_sizes[3];
    int N = in_sizes[0] / (14 * 14 * 30);
    int nblocks = (n_cells + BLOCK - 1) / BLOCK;

    hipLaunchKernelGGL(k_yolo, dim3(nblocks), dim3(BLOCK), 0, stream,
                       pred, tbox4, tcls4, mask, partial, n_cells);
    hipLaunchKernelGGL(k_final, dim3(1), dim3(BLOCK), 0, stream,
                       partial, nblocks, out, 1.0f / (float)N);
}